// Round 5
// baseline (121.054 us; speedup 1.0000x reference)
//
#include <hip/hip_runtime.h>

#define B 16
#define S 4096
#define V 128
#define TRUNC 11
#define T_LIM (S - TRUNC)   // 4085

#define NC 512              // chunks over t
#define CT (S / NC)         // 8
#define BV (B * V)          // 2048

// log2(0.99), 1/0.99
#define LOG2_GAMMA (-0.014499569695115089f)
#define INV_GAMMA 1.0101010101010102f

__device__ __forceinline__ float log_sigmoid(float x) {
    float e = __expf(-fabsf(x));
    return fminf(x, 0.0f) - __logf(1.0f + e);
}

// Thread (c, b, v4): fully-unrolled branch-free CT=8 scan of one chunk.
//   A = sum w[t]*ls[t]*acc[t],  W = sum w[t]*ls[t],  L = sum_{t<T} lp[t]
// Stores TRANSPOSED [bv][NC] so combine reads are coalesced float4.
__global__ __launch_bounds__(256) void partials_kernel(
    const float4* __restrict__ lp,   // [S][B][V/4]
    const float4* __restrict__ lg,   // [B][S][V/4]
    float* __restrict__ pA,          // [BV][NC]
    float* __restrict__ pW,
    float* __restrict__ pL)
{
    int tid = blockIdx.x * blockDim.x + threadIdx.x;   // 262144 threads
    int v4 = tid & (V / 4 - 1);          // 0..31
    int b  = (tid >> 5) & (B - 1);       // 0..15
    int c  = tid >> 9;                   // 0..NC-1
    int t0 = c * CT;

    const float4* lp_p = lp + (size_t)t0 * (B * V / 4) + b * (V / 4) + v4;
    const float4* lg_p = lg + (size_t)b * (S * V / 4) + (size_t)t0 * (V / 4) + v4;

    float w = exp2f(LOG2_GAMMA * (float)(S - t0));

    float ax = 0.f, ay = 0.f, az = 0.f, aw = 0.f;
    float Ax = 0.f, Ay = 0.f, Az = 0.f, Aw = 0.f;
    float Wx = 0.f, Wy = 0.f, Wz = 0.f, Ww = 0.f;

    #pragma unroll
    for (int i = 0; i < CT; ++i) {
        float4 l = lp_p[(size_t)i * (B * V / 4)];
        float4 x = lg_p[(size_t)i * (V / 4)];
        // branch-free truncation mask (cndmask + fma; keeps loads hoistable)
        float m = (t0 + i < T_LIM) ? 1.0f : 0.0f;
        ax = fmaf(m, l.x, ax);
        ay = fmaf(m, l.y, ay);
        az = fmaf(m, l.z, az);
        aw = fmaf(m, l.w, aw);
        float sx = w * log_sigmoid(x.x);
        float sy = w * log_sigmoid(x.y);
        float sz = w * log_sigmoid(x.z);
        float sw = w * log_sigmoid(x.w);
        Ax = fmaf(sx, ax, Ax);
        Ay = fmaf(sy, ay, Ay);
        Az = fmaf(sz, az, Az);
        Aw = fmaf(sw, aw, Aw);
        Wx += sx; Wy += sy; Wz += sz; Ww += sw;
        w *= INV_GAMMA;
    }

    size_t base = (size_t)(b * V + v4 * 4) * NC + c;   // [bv][c]
    pA[base]          = Ax; pA[base + NC]     = Ay;
    pA[base + 2 * NC] = Az; pA[base + 3 * NC] = Aw;
    pW[base]          = Wx; pW[base + NC]     = Wy;
    pW[base + 2 * NC] = Wz; pW[base + 3 * NC] = Ww;
    pL[base]          = ax; pL[base + NC]     = ay;
    pL[base + 2 * NC] = az; pL[base + 3 * NC] = aw;
}

// One wave per (b,v). Lane l owns chunks 4l..4l+3 (segment 0) and
// 256+4l..256+4l+3 (segment 1) as two coalesced float4 loads per array.
// Two-round wave scan of L gives exclusive chunk prefixes.
__global__ __launch_bounds__(256) void combine_kernel(
    const float4* __restrict__ pA,   // [BV][NC/4]
    const float4* __restrict__ pW,
    const float4* __restrict__ pL,
    float* __restrict__ out)
{
    int gtid = blockIdx.x * blockDim.x + threadIdx.x;
    int bv   = gtid >> 6;
    int lane = threadIdx.x & 63;
    if (bv >= BV) return;

    const int nc4 = NC / 4;              // 128 float4 per row
    const float4* rA = pA + (size_t)bv * nc4;
    const float4* rW = pW + (size_t)bv * nc4;
    const float4* rL = pL + (size_t)bv * nc4;

    float4 A0 = rA[lane], A1 = rA[64 + lane];
    float4 W0 = rW[lane], W1 = rW[64 + lane];
    float4 L0 = rL[lane], L1 = rL[64 + lane];

    // intra-lane exclusive prefixes, segment 0
    float a1 = L0.x, a2 = a1 + L0.y, a3 = a2 + L0.z, s0 = a3 + L0.w;
    // segment 1
    float b1 = L1.x, b2 = b1 + L1.y, b3 = b2 + L1.z, s1 = b3 + L1.w;

    // wave scans (inclusive), then exclusive
    float sc0 = s0, sc1 = s1;
    #pragma unroll
    for (int off = 1; off < 64; off <<= 1) {
        float n0 = __shfl_up(sc0, off, 64);
        float n1 = __shfl_up(sc1, off, 64);
        if (lane >= off) { sc0 += n0; sc1 += n1; }
    }
    float tot0  = __shfl(sc0, 63, 64);   // total of segment 0
    float base0 = sc0 - s0;              // exclusive prefix, segment 0
    float base1 = tot0 + sc1 - s1;       // exclusive prefix, segment 1

    float E = A0.x + A0.y + A0.z + A0.w + A1.x + A1.y + A1.z + A1.w;
    E = fmaf(base0,      W0.x, E);
    E = fmaf(base0 + a1, W0.y, E);
    E = fmaf(base0 + a2, W0.z, E);
    E = fmaf(base0 + a3, W0.w, E);
    E = fmaf(base1,      W1.x, E);
    E = fmaf(base1 + b1, W1.y, E);
    E = fmaf(base1 + b2, W1.z, E);
    E = fmaf(base1 + b3, W1.w, E);

    #pragma unroll
    for (int off = 32; off > 0; off >>= 1)
        E += __shfl_down(E, off, 64);

    if (lane == 0) out[bv] = E;
}

// Fallback (ws too small): one thread per (b, v4), full-S scan, direct out.
__global__ __launch_bounds__(256) void direct_kernel(
    const float4* __restrict__ lp,
    const float4* __restrict__ lg,
    float4* __restrict__ out)
{
    int tid = blockIdx.x * blockDim.x + threadIdx.x;
    if (tid >= B * V / 4) return;
    int v4 = tid & (V / 4 - 1);
    int b  = tid >> 5;

    const float4* lp_p = lp + b * (V / 4) + v4;
    const float4* lg_p = lg + (size_t)b * (S * V / 4) + v4;

    float w = exp2f(LOG2_GAMMA * (float)S);
    float ax = 0.f, ay = 0.f, az = 0.f, aw = 0.f;
    float Ax = 0.f, Ay = 0.f, Az = 0.f, Aw = 0.f;
    for (int t = 0; t < S; ++t) {
        float4 l = lp_p[(size_t)t * (B * V / 4)];
        float4 x = lg_p[(size_t)t * (V / 4)];
        if (t < T_LIM) { ax += l.x; ay += l.y; az += l.z; aw += l.w; }
        Ax = fmaf(w * log_sigmoid(x.x), ax, Ax);
        Ay = fmaf(w * log_sigmoid(x.y), ay, Ay);
        Az = fmaf(w * log_sigmoid(x.z), az, Az);
        Aw = fmaf(w * log_sigmoid(x.w), aw, Aw);
        w *= INV_GAMMA;
    }
    out[tid] = make_float4(Ax, Ay, Az, Aw);
}

extern "C" void kernel_launch(void* const* d_in, const int* in_sizes, int n_in,
                              void* d_out, int out_size, void* d_ws, size_t ws_size,
                              hipStream_t stream)
{
    const float4* lp = (const float4*)d_in[0];   // log_probs [S,B,V] f32
    const float4* lg = (const float4*)d_in[1];   // logits    [B,S,V] f32
    float* out = (float*)d_out;                   // [B,V] f32

    size_t per = (size_t)NC * BV;                 // floats per partial array

    if (per * 3 * sizeof(float) > ws_size) {
        direct_kernel<<<(B * V / 4 + 255) / 256, 256, 0, stream>>>(
            lp, lg, (float4*)d_out);
        return;
    }

    float* pA = (float*)d_ws;
    float* pW = pA + per;
    float* pL = pW + per;

    int threads1 = NC * (B * V / 4);              // 262144 -> 1024 blocks
    partials_kernel<<<threads1 / 256, 256, 0, stream>>>(lp, lg, pA, pW, pL);

    int threads2 = BV * 64;                       // 131072 -> 512 blocks
    combine_kernel<<<threads2 / 256, 256, 0, stream>>>(
        (const float4*)pA, (const float4*)pW, (const float4*)pL, out);
}

// Round 6
// 115.730 us; speedup vs baseline: 1.0460x; 1.0460x over previous
//
#include <hip/hip_runtime.h>

#define B 16
#define S 4096
#define V 128
#define TRUNC 11
#define T_LIM (S - TRUNC)   // 4085

#define NC 512              // chunks over t
#define CT (S / NC)         // 8
#define BV (B * V)          // 2048
#define BVq (B * V / 4)     // 512 float4 per t-slice

// log2(0.99), 1/0.99
#define LOG2_GAMMA (-0.014499569695115089f)
#define INV_GAMMA 1.0101010101010102f

__device__ __forceinline__ float log_sigmoid(float x) {
    float e = __expf(-fabsf(x));
    return fminf(x, 0.0f) - __logf(1.0f + e);
}

// Thread (c, b, v4): CT=8 chunk scan, ALL 16 float4 loads issued up-front
// (max memory-level parallelism), then compute.
//   A = sum w[t]*ls[t]*acc[t],  W = sum w[t]*ls[t],  L = sum_{t<T} lp[t]
// Stores in NATURAL [c][bv] layout: p*4[tid] — one coalesced full-line
// float4 store per array. (R5's [bv][NC] scatter caused 10x write
// amplification: 114 MB vs 12 MB payload.)
__global__ __launch_bounds__(256, 4) void partials_kernel(
    const float4* __restrict__ lp,   // [S][B][V/4]
    const float4* __restrict__ lg,   // [B][S][V/4]
    float4* __restrict__ pA,         // [NC][BVq]
    float4* __restrict__ pW,
    float4* __restrict__ pL)
{
    int tid = blockIdx.x * blockDim.x + threadIdx.x;   // 262144 threads
    int v4 = tid & (V / 4 - 1);          // 0..31
    int b  = (tid >> 5) & (B - 1);       // 0..15
    int c  = tid >> 9;                   // 0..NC-1
    int t0 = c * CT;

    const float4* lp_p = lp + (size_t)t0 * BVq + b * (V / 4) + v4;
    const float4* lg_p = lg + (size_t)b * (S * V / 4) + (size_t)t0 * (V / 4) + v4;

    // burst-load everything (16 outstanding vector loads per lane)
    float4 Lb[CT], Xb[CT];
    #pragma unroll
    for (int i = 0; i < CT; ++i) Lb[i] = lp_p[(size_t)i * BVq];
    #pragma unroll
    for (int i = 0; i < CT; ++i) Xb[i] = lg_p[(size_t)i * (V / 4)];

    float w = exp2f(LOG2_GAMMA * (float)(S - t0));

    float ax = 0.f, ay = 0.f, az = 0.f, aw = 0.f;
    float Ax = 0.f, Ay = 0.f, Az = 0.f, Aw = 0.f;
    float Wx = 0.f, Wy = 0.f, Wz = 0.f, Ww = 0.f;

    #pragma unroll
    for (int i = 0; i < CT; ++i) {
        float m = (t0 + i < T_LIM) ? 1.0f : 0.0f;   // branch-free truncation
        ax = fmaf(m, Lb[i].x, ax);
        ay = fmaf(m, Lb[i].y, ay);
        az = fmaf(m, Lb[i].z, az);
        aw = fmaf(m, Lb[i].w, aw);
        float sx = w * log_sigmoid(Xb[i].x);
        float sy = w * log_sigmoid(Xb[i].y);
        float sz = w * log_sigmoid(Xb[i].z);
        float sw = w * log_sigmoid(Xb[i].w);
        Ax = fmaf(sx, ax, Ax);
        Ay = fmaf(sy, ay, Ay);
        Az = fmaf(sz, az, Az);
        Aw = fmaf(sw, aw, Aw);
        Wx += sx; Wy += sy; Wz += sz; Ww += sw;
        w *= INV_GAMMA;
    }

    pA[tid] = make_float4(Ax, Ay, Az, Aw);
    pW[tid] = make_float4(Wx, Wy, Wz, Ww);
    pL[tid] = make_float4(ax, ay, az, aw);
}

// One wave per (b,v). Lane l owns chunks 8l..8l+7: 24 scattered scalar
// loads from the 12 MB cache-resident partials (reads absorb the
// transpose — cheap; scattered STORES were the R5 disaster).
// Intra-lane prefix over 8 chunks + wave scan -> exclusive chunk prefixes.
__global__ __launch_bounds__(256) void combine_kernel(
    const float* __restrict__ pA,    // [NC][BV] scalar view
    const float* __restrict__ pW,
    const float* __restrict__ pL,
    float* __restrict__ out)
{
    int gtid = blockIdx.x * blockDim.x + threadIdx.x;
    int bv   = gtid >> 6;
    int lane = threadIdx.x & 63;
    if (bv >= BV) return;

    int c0 = lane * 8;                   // first chunk this lane owns
    size_t base = (size_t)c0 * BV + bv;

    float Aj[8], Wj[8], Lj[8];
    #pragma unroll
    for (int j = 0; j < 8; ++j) {
        size_t idx = base + (size_t)j * BV;
        Aj[j] = pA[idx];
        Wj[j] = pW[idx];
        Lj[j] = pL[idx];
    }

    // intra-lane exclusive prefixes of L
    float p[8];
    float run = 0.f;
    #pragma unroll
    for (int j = 0; j < 8; ++j) { p[j] = run; run += Lj[j]; }
    float s = run;                       // lane total

    // inclusive wave scan of s -> exclusive lane base
    float scan = s;
    #pragma unroll
    for (int off = 1; off < 64; off <<= 1) {
        float n = __shfl_up(scan, off, 64);
        if (lane >= off) scan += n;
    }
    float lbase = scan - s;

    float E = 0.f;
    #pragma unroll
    for (int j = 0; j < 8; ++j)
        E = fmaf(lbase + p[j], Wj[j], E + Aj[j]);

    #pragma unroll
    for (int off = 32; off > 0; off >>= 1)
        E += __shfl_down(E, off, 64);

    if (lane == 0) out[bv] = E;
}

// Fallback (ws too small): one thread per (b, v4), full-S scan, direct out.
__global__ __launch_bounds__(256) void direct_kernel(
    const float4* __restrict__ lp,
    const float4* __restrict__ lg,
    float4* __restrict__ out)
{
    int tid = blockIdx.x * blockDim.x + threadIdx.x;
    if (tid >= B * V / 4) return;
    int v4 = tid & (V / 4 - 1);
    int b  = tid >> 5;

    const float4* lp_p = lp + b * (V / 4) + v4;
    const float4* lg_p = lg + (size_t)b * (S * V / 4) + v4;

    float w = exp2f(LOG2_GAMMA * (float)S);
    float ax = 0.f, ay = 0.f, az = 0.f, aw = 0.f;
    float Ax = 0.f, Ay = 0.f, Az = 0.f, Aw = 0.f;
    for (int t = 0; t < S; ++t) {
        float4 l = lp_p[(size_t)t * BVq];
        float4 x = lg_p[(size_t)t * (V / 4)];
        if (t < T_LIM) { ax += l.x; ay += l.y; az += l.z; aw += l.w; }
        Ax = fmaf(w * log_sigmoid(x.x), ax, Ax);
        Ay = fmaf(w * log_sigmoid(x.y), ay, Ay);
        Az = fmaf(w * log_sigmoid(x.z), az, Az);
        Aw = fmaf(w * log_sigmoid(x.w), aw, Aw);
        w *= INV_GAMMA;
    }
    out[tid] = make_float4(Ax, Ay, Az, Aw);
}

extern "C" void kernel_launch(void* const* d_in, const int* in_sizes, int n_in,
                              void* d_out, int out_size, void* d_ws, size_t ws_size,
                              hipStream_t stream)
{
    const float4* lp = (const float4*)d_in[0];   // log_probs [S,B,V] f32
    const float4* lg = (const float4*)d_in[1];   // logits    [B,S,V] f32
    float* out = (float*)d_out;                   // [B,V] f32

    size_t per = (size_t)NC * BV;                 // floats per partial array

    if (per * 3 * sizeof(float) > ws_size) {
        direct_kernel<<<(B * V / 4 + 255) / 256, 256, 0, stream>>>(
            lp, lg, (float4*)d_out);
        return;
    }

    float* pA = (float*)d_ws;
    float* pW = pA + per;
    float* pL = pW + per;

    int threads1 = NC * (B * V / 4);              // 262144 -> 1024 blocks
    partials_kernel<<<threads1 / 256, 256, 0, stream>>>(
        lp, lg, (float4*)pA, (float4*)pW, (float4*)pL);

    int threads2 = BV * 64;                       // 131072 -> 512 blocks
    combine_kernel<<<threads2 / 256, 256, 0, stream>>>(pA, pW, pL, out);
}

// Round 7
// 114.537 us; speedup vs baseline: 1.0569x; 1.0104x over previous
//
#include <hip/hip_runtime.h>

#define B 16
#define S 4096
#define V 128
#define TRUNC 11
#define T_LIM (S - TRUNC)   // 4085

#define NC 128              // chunks over t (compile-time)
#define CT (S / NC)         // 32
#define BV (B * V)          // 2048

// log2(0.99), 1/0.99
#define LOG2_GAMMA (-0.014499569695115089f)
#define INV_GAMMA 1.0101010101010102f

__device__ __forceinline__ float log_sigmoid(float x) {
    float e = __expf(-fabsf(x));
    return fminf(x, 0.0f) - __logf(1.0f + e);
}

// Thread (c, b, v4) computes per-v chunk partials:
//   A = sum_{t in chunk} w[t]*ls[t]*local_acc[t]
//   W = sum_{t in chunk} w[t]*ls[t]
//   L = sum_{t in chunk, t<T} lp[t]
// Natural [c][b][v] layout: one coalesced full-line float4 store per array.
// NOTE (R5/R6 post-mortem): the ~37 us window of this kernel is dominated by
// the harness's 268 MB ws-poison draining MALL->HBM underneath us; kernel-side
// variations (burst loads, NC, store layout) move it <5 us.
__global__ __launch_bounds__(256) void partials_kernel(
    const float4* __restrict__ lp,   // [S][B][V/4]
    const float4* __restrict__ lg,   // [B][S][V/4]
    float4* __restrict__ pA,         // [NC][B][V/4]
    float4* __restrict__ pW,
    float4* __restrict__ pL)
{
    int tid = blockIdx.x * blockDim.x + threadIdx.x;   // 65536 threads
    int v4 = tid & (V / 4 - 1);          // 0..31
    int b  = (tid >> 5) & (B - 1);       // 0..15
    int c  = tid >> 9;                   // 0..NC-1
    int t0 = c * CT;

    const float4* lp_p = lp + (size_t)t0 * (B * V / 4) + b * (V / 4) + v4;
    const float4* lg_p = lg + (size_t)b * (S * V / 4) + (size_t)t0 * (V / 4) + v4;

    float w = exp2f(LOG2_GAMMA * (float)(S - t0));

    float ax = 0.f, ay = 0.f, az = 0.f, aw = 0.f;
    float Ax = 0.f, Ay = 0.f, Az = 0.f, Aw = 0.f;
    float Wx = 0.f, Wy = 0.f, Wz = 0.f, Ww = 0.f;

    #pragma unroll 8
    for (int i = 0; i < CT; ++i) {
        int t = t0 + i;
        float4 l = lp_p[(size_t)i * (B * V / 4)];
        float4 x = lg_p[(size_t)i * (V / 4)];
        if (t < T_LIM) {                 // wave-uniform
            ax += l.x; ay += l.y; az += l.z; aw += l.w;
        }
        float sx = w * log_sigmoid(x.x);
        float sy = w * log_sigmoid(x.y);
        float sz = w * log_sigmoid(x.z);
        float sw = w * log_sigmoid(x.w);
        Ax = fmaf(sx, ax, Ax);
        Ay = fmaf(sy, ay, Ay);
        Az = fmaf(sz, az, Az);
        Aw = fmaf(sw, aw, Aw);
        Wx += sx; Wy += sy; Wz += sz; Ww += sw;
        w *= INV_GAMMA;
    }

    pA[tid] = make_float4(Ax, Ay, Az, Aw);
    pW[tid] = make_float4(Wx, Wy, Wz, Ww);
    pL[tid] = make_float4(ax, ay, az, aw);
}

// One wave per (b,v). Lane l owns chunks 2l and 2l+1 — 6 scattered scalar
// loads per lane from the 3 MB cache-resident partials (~50 MB of line
// traffic total; the R6 8-chunks/lane variant generated ~196 MB and
// regressed). Wave scan of L -> exclusive chunk prefixes.
__global__ __launch_bounds__(256) void combine_kernel(
    const float* __restrict__ pA,    // [NC][BV]
    const float* __restrict__ pW,
    const float* __restrict__ pL,
    float* __restrict__ out)
{
    int gtid = blockIdx.x * blockDim.x + threadIdx.x;
    int bv   = gtid >> 6;
    int lane = threadIdx.x & 63;
    if (bv >= BV) return;

    size_t i0 = (size_t)(lane * 2) * BV + bv;
    float A0 = pA[i0], A1 = pA[i0 + BV];
    float W0 = pW[i0], W1 = pW[i0 + BV];
    float L0 = pL[i0], L1 = pL[i0 + BV];

    float s = L0 + L1;                   // lane total of L

    // inclusive wave scan of s, then make exclusive
    float scan = s;
    #pragma unroll
    for (int off = 1; off < 64; off <<= 1) {
        float n = __shfl_up(scan, off, 64);
        if (lane >= off) scan += n;
    }
    float base = scan - s;               // prefix before chunk 2*lane

    float E = A0 + A1;
    E = fmaf(base,      W0, E);
    E = fmaf(base + L0, W1, E);

    #pragma unroll
    for (int off = 32; off > 0; off >>= 1)
        E += __shfl_down(E, off, 64);

    if (lane == 0) out[bv] = E;
}

// Fallback (ws too small): one thread per (b, v4), full-S scan, direct out.
__global__ __launch_bounds__(256) void direct_kernel(
    const float4* __restrict__ lp,
    const float4* __restrict__ lg,
    float4* __restrict__ out)
{
    int tid = blockIdx.x * blockDim.x + threadIdx.x;
    if (tid >= B * V / 4) return;
    int v4 = tid & (V / 4 - 1);
    int b  = tid >> 5;

    const float4* lp_p = lp + b * (V / 4) + v4;
    const float4* lg_p = lg + (size_t)b * (S * V / 4) + v4;

    float w = exp2f(LOG2_GAMMA * (float)S);
    float ax = 0.f, ay = 0.f, az = 0.f, aw = 0.f;
    float Ax = 0.f, Ay = 0.f, Az = 0.f, Aw = 0.f;
    for (int t = 0; t < S; ++t) {
        float4 l = lp_p[(size_t)t * (B * V / 4)];
        float4 x = lg_p[(size_t)t * (V / 4)];
        if (t < T_LIM) { ax += l.x; ay += l.y; az += l.z; aw += l.w; }
        Ax = fmaf(w * log_sigmoid(x.x), ax, Ax);
        Ay = fmaf(w * log_sigmoid(x.y), ay, Ay);
        Az = fmaf(w * log_sigmoid(x.z), az, Az);
        Aw = fmaf(w * log_sigmoid(x.w), aw, Aw);
        w *= INV_GAMMA;
    }
    out[tid] = make_float4(Ax, Ay, Az, Aw);
}

extern "C" void kernel_launch(void* const* d_in, const int* in_sizes, int n_in,
                              void* d_out, int out_size, void* d_ws, size_t ws_size,
                              hipStream_t stream)
{
    const float4* lp = (const float4*)d_in[0];   // log_probs [S,B,V] f32
    const float4* lg = (const float4*)d_in[1];   // logits    [B,S,V] f32
    float* out = (float*)d_out;                   // [B,V] f32

    size_t per = (size_t)NC * BV;                 // floats per partial array

    if (per * 3 * sizeof(float) > ws_size) {
        direct_kernel<<<(B * V / 4 + 255) / 256, 256, 0, stream>>>(
            lp, lg, (float4*)d_out);
        return;
    }

    float* pA = (float*)d_ws;
    float* pW = pA + per;
    float* pL = pW + per;

    int threads1 = NC * (B * V / 4);              // 65536
    partials_kernel<<<threads1 / 256, 256, 0, stream>>>(
        lp, lg, (float4*)pA, (float4*)pW, (float4*)pL);

    int threads2 = BV * 64;                       // 131072
    combine_kernel<<<threads2 / 256, 256, 0, stream>>>(pA, pW, pL, out);
}